// Round 6
// baseline (324.985 us; speedup 1.0000x reference)
//
#include <hip/hip_runtime.h>

// CRF forward: batched-matrix scan on MFMA.
// State = E[state i][batch b] (32x32) per wave, exp domain.
//   fwd (t=0..255, never masked since len>=256):  E' = (Et . E) o EH_t
//   bwd (t=511..256, handles all masks):          E' = Et^T . (E o EH_t), frozen cols -> init
// A-operand (Et or Et^T) is CONSTANT in registers. B = E bf16 frags; D f32 C-layout.
// C-layout: lane l holds col = l&31 (batch), rows (r&3)+8(r>>2)+4(l>>5).
// EH gather: rows are 4-contiguous in i -> 4 x global_load_dwordx4 per lane per step.
// Per-column exact pow2 renorm every 4 steps. Combine: out = ln2*(Ra+Rb+log2(sum_i EA*EB)).

#define T_LEN 512
#define B_SZ  2048
#define K_SZ  32
#define TBK   65536
#define START_S 29
#define END_S   30
#define L2E 1.4426950408889634f
#define LN2 0.6931471805599453f
#define DEPTH 4

#if defined(__has_builtin) && __has_builtin(__builtin_amdgcn_exp2f)
#define EXP2F(x) __builtin_amdgcn_exp2f(x)
#else
#define EXP2F(x) exp2f(x)
#endif
#if defined(__has_builtin) && __has_builtin(__builtin_amdgcn_logf)
#define LOG2F(x) __builtin_amdgcn_logf(x)
#else
#define LOG2F(x) log2f(x)
#endif

typedef float f32x16 __attribute__((ext_vector_type(16)));
typedef short s16x8  __attribute__((ext_vector_type(8)));

static __device__ __forceinline__ unsigned cvtpk(float lo, float hi) {
  unsigned r;
  asm("v_cvt_pk_bf16_f32 %0, %1, %2" : "=v"(r) : "v"(lo), "v"(hi));
  return r;
}
static __device__ __forceinline__ void swap32(unsigned &a, unsigned &b) {
  asm("v_permlane32_swap_b32 %0, %1" : "+v"(a), "+v"(b));
}
static __device__ __forceinline__ s16x8 pack8(unsigned a0, unsigned a1, unsigned a2, unsigned a3) {
  union { unsigned u[4]; s16x8 v; } t;
  t.u[0] = a0; t.u[1] = a1; t.u[2] = a2; t.u[3] = a3;
  return t.v;
}

// f32 C-layout -> bf16 B-operand frags (k halves). Verified by round-5 pass.
static __device__ __forceinline__ void toB(const f32x16& d, s16x8& B1, s16x8& B2) {
  unsigned c0 = cvtpk(d[0],  d[1]),  c1 = cvtpk(d[2],  d[3]);
  unsigned c2 = cvtpk(d[4],  d[5]),  c3 = cvtpk(d[6],  d[7]);
  swap32(c0, c2); swap32(c1, c3);
  B1 = pack8(c0, c1, c2, c3);
  unsigned e0 = cvtpk(d[8],  d[9]),  e1 = cvtpk(d[10], d[11]);
  unsigned e2 = cvtpk(d[12], d[13]), e3 = cvtpk(d[14], d[15]);
  swap32(e0, e2); swap32(e1, e3);
  B2 = pack8(e0, e1, e2, e3);
}

template<int FWD>
static __device__ __forceinline__ void scan_body(
    const float* __restrict__ hid, const float* __restrict__ msk,
    const float* __restrict__ trans,
    float* __restrict__ E_out, int* __restrict__ R_out, int g)
{
  const int l   = threadIdx.x & 63;
  const int col = l & 31;              // batch within group
  const int h2  = l >> 5;
  const int b   = g * K_SZ + col;

  // Constant A operand: fwd A[row][k] = e^trans[row][k]; bwd A[row][k] = e^trans[k][row]
  s16x8 A1, A2;
  {
    float v[16];
    #pragma unroll
    for (int jj = 0; jj < 8; ++jj) {
      const int k1 = 8 * h2 + jj, k2 = 16 + 8 * h2 + jj;
      v[jj]     = FWD ? trans[col * K_SZ + k1] : trans[k1 * K_SZ + col];
      v[8 + jj] = FWD ? trans[col * K_SZ + k2] : trans[k2 * K_SZ + col];
    }
    A1 = pack8(cvtpk(EXP2F(v[0] * L2E),  EXP2F(v[1] * L2E)),
               cvtpk(EXP2F(v[2] * L2E),  EXP2F(v[3] * L2E)),
               cvtpk(EXP2F(v[4] * L2E),  EXP2F(v[5] * L2E)),
               cvtpk(EXP2F(v[6] * L2E),  EXP2F(v[7] * L2E)));
    A2 = pack8(cvtpk(EXP2F(v[8]  * L2E), EXP2F(v[9]  * L2E)),
               cvtpk(EXP2F(v[10] * L2E), EXP2F(v[11] * L2E)),
               cvtpk(EXP2F(v[12] * L2E), EXP2F(v[13] * L2E)),
               cvtpk(EXP2F(v[14] * L2E), EXP2F(v[15] * L2E)));
  }

  f32x16 d, dini;
  #pragma unroll
  for (int r = 0; r < 16; ++r) {
    const int row = (r & 3) + 8 * (r >> 2) + 4 * h2;
    if (FWD) { d[r] = (row == START_S) ? 1.0f : 0.0f; dini[r] = 0.0f; }
    else     { dini[r] = EXP2F(trans[END_S * K_SZ + row] * L2E); d[r] = dini[r]; }
  }

  const long hstep = FWD ? (long)TBK : -(long)TBK;
  const long mstep = FWD ? (long)B_SZ : -(long)B_SZ;
  const float* hp = hid + (FWD ? 0 : (long)(T_LEN - 1) * TBK) + (long)b * K_SZ + 4 * h2;
  const float* mp = msk + (FWD ? 0 : (long)(T_LEN - 1) * B_SZ) + b;

  float4 hr[DEPTH][4];
  float  mr[DEPTH];
  #pragma unroll
  for (int k = 0; k < DEPTH; ++k) {
    const float* p = hp + (long)k * hstep;
    hr[k][0] = *(const float4*)(p);
    hr[k][1] = *(const float4*)(p + 8);
    hr[k][2] = *(const float4*)(p + 16);
    hr[k][3] = *(const float4*)(p + 24);
    mr[k] = FWD ? 0.0f : mp[(long)k * mstep];
  }

  int R = 0;
  for (int c = 0; c < 64; ++c) {           // 64 x DEPTH = 256 steps
    #pragma unroll
    for (int k = 0; k < DEPTH; ++k) {
      const float4 e0 = hr[k][0], e1 = hr[k][1], e2 = hr[k][2], e3 = hr[k][3];
      const float  mv = FWD ? 0.0f : mr[k];
      {
        const float* p = hp + (long)(c * DEPTH + k + DEPTH) * hstep;   // stays in [0,512)
        hr[k][0] = *(const float4*)(p);
        hr[k][1] = *(const float4*)(p + 8);
        hr[k][2] = *(const float4*)(p + 16);
        hr[k][3] = *(const float4*)(p + 24);
        if (!FWD) mr[k] = mp[(long)(c * DEPTH + k + DEPTH) * mstep];
      }
      f32x16 eh;
      eh[0]  = EXP2F(e0.x * L2E); eh[1]  = EXP2F(e0.y * L2E);
      eh[2]  = EXP2F(e0.z * L2E); eh[3]  = EXP2F(e0.w * L2E);
      eh[4]  = EXP2F(e1.x * L2E); eh[5]  = EXP2F(e1.y * L2E);
      eh[6]  = EXP2F(e1.z * L2E); eh[7]  = EXP2F(e1.w * L2E);
      eh[8]  = EXP2F(e2.x * L2E); eh[9]  = EXP2F(e2.y * L2E);
      eh[10] = EXP2F(e2.z * L2E); eh[11] = EXP2F(e2.w * L2E);
      eh[12] = EXP2F(e3.x * L2E); eh[13] = EXP2F(e3.y * L2E);
      eh[14] = EXP2F(e3.z * L2E); eh[15] = EXP2F(e3.w * L2E);

      if (FWD) {
        s16x8 B1, B2; toB(d, B1, B2);
        f32x16 z = {0.0f};
        d = __builtin_amdgcn_mfma_f32_32x32x16_bf16(A1, B1, z, 0, 0, 0);
        d = __builtin_amdgcn_mfma_f32_32x32x16_bf16(A2, B2, d, 0, 0, 0);
        #pragma unroll
        for (int r = 0; r < 16; ++r) d[r] *= eh[r];
      } else {
        #pragma unroll
        for (int r = 0; r < 16; ++r) d[r] *= eh[r];
        s16x8 B1, B2; toB(d, B1, B2);
        f32x16 z = {0.0f};
        f32x16 dn = __builtin_amdgcn_mfma_f32_32x32x16_bf16(A1, B1, z, 0, 0, 0);
        dn = __builtin_amdgcn_mfma_f32_32x32x16_bf16(A2, B2, dn, 0, 0, 0);
        const bool m = mv > 0.5f;            // masked: stay at init
        #pragma unroll
        for (int r = 0; r < 16; ++r) d[r] = m ? dini[r] : dn[r];
      }

      if (k == DEPTH - 1) {                  // exact pow2 per-column renorm
        const float c0 = __shfl(d[0], col);  // lower half's row 0 of this column
        const unsigned bb = __float_as_uint(c0);
        int   s  = (int)((bb >> 23) & 255) - 127;
        float sc = __uint_as_float((unsigned)(127 - s) << 23);
        if (!FWD) { const bool m = mv > 0.5f; sc = m ? 1.0f : sc; s = m ? 0 : s; }
        #pragma unroll
        for (int r = 0; r < 16; ++r) d[r] *= sc;
        R += s;
      }
    }
  }

  float* eo = E_out + (long)b * K_SZ + 4 * h2;
  #pragma unroll
  for (int q = 0; q < 4; ++q) {
    float4 o = { d[4 * q + 0], d[4 * q + 1], d[4 * q + 2], d[4 * q + 3] };
    *(float4*)(eo + 8 * q) = o;
  }
  if (h2 == 0) R_out[b] = R;
}

__global__ __launch_bounds__(64, 1) void crf_scan(
    const float* __restrict__ hid, const float* __restrict__ msk,
    const float* __restrict__ trans,
    float* __restrict__ EA, int* __restrict__ RA,
    float* __restrict__ EB, int* __restrict__ RB)
{
  const int bid = blockIdx.x;
  if (bid < 64) scan_body<1>(hid, msk, trans, EA, RA, bid);
  else          scan_body<0>(hid, msk, trans, EB, RB, bid - 64);
}

__global__ __launch_bounds__(256) void crf_comb(
    const float* __restrict__ EA, const int* __restrict__ RA,
    const float* __restrict__ EB, const int* __restrict__ RB,
    float* __restrict__ out)
{
  const int tx = threadIdx.x;
  const int i  = tx & 31;
  const int g  = tx >> 5;
  const int b  = blockIdx.x * 8 + g;

  const float va = EA[b * K_SZ + i], vb = EB[b * K_SZ + i];
  float v = LOG2F(va) + LOG2F(vb);        // -inf for unreachable states, no NaN
  float M = v;
  M = fmaxf(M, __shfl_xor(M, 1));
  M = fmaxf(M, __shfl_xor(M, 2));
  M = fmaxf(M, __shfl_xor(M, 4));
  M = fmaxf(M, __shfl_xor(M, 8));
  M = fmaxf(M, __shfl_xor(M, 16));
  float x = EXP2F(v - M);
  x += __shfl_xor(x, 1);
  x += __shfl_xor(x, 2);
  x += __shfl_xor(x, 4);
  x += __shfl_xor(x, 8);
  x += __shfl_xor(x, 16);
  if (i == 0) out[b] = ((float)(RA[b] + RB[b]) + M + LOG2F(x)) * LN2;
}

extern "C" void kernel_launch(void* const* d_in, const int* in_sizes, int n_in,
                              void* d_out, int out_size, void* d_ws, size_t ws_size,
                              hipStream_t stream) {
  const float* hid   = (const float*)d_in[0];   // (512, 2048, 32) f32
  const float* msk   = (const float*)d_in[1];   // (512, 2048)     f32
  const float* trans = (const float*)d_in[2];   // (32, 32)        f32
  float* out = (float*)d_out;                   // (2048,)         f32

  float* EA = (float*)d_ws;                       // 2048*32 f32
  float* EB = EA + (size_t)B_SZ * K_SZ;           // 2048*32 f32
  int*   RA = (int*)(EB + (size_t)B_SZ * K_SZ);   // 2048 i32
  int*   RB = RA + B_SZ;                          // 2048 i32

  crf_scan<<<dim3(128), dim3(64), 0, stream>>>(hid, msk, trans, EA, RA, EB, RB);
  crf_comb<<<dim3(B_SZ / 8), dim3(256), 0, stream>>>(EA, RA, EB, RB, out);
}